// Round 5
// baseline (6988.603 us; speedup 1.0000x reference)
//
#include <hip/hip_runtime.h>
#include <hip/hip_bf16.h>
#include <cstddef>

#define D 32
#define EF 64
#define DD 1024  // D*D
#define NSTEPS 3

typedef float floatx4 __attribute__((ext_vector_type(4)));  // native vec for NT builtins

__device__ __forceinline__ float sigmoidf_(float x) { return 1.0f / (1.0f + expf(-x)); }

__device__ __forceinline__ float wload(const float* p) { return __builtin_nontemporal_load(p); }
__device__ __forceinline__ float wload(const __hip_bfloat16* p) {
  return __bfloat162float(*p);
}

// ---------------------------------------------------------------------------
// W_e = efeat @ W_edge + b_edge   (E x 1024), tile: 32 edges x 256 cols/block
// ---------------------------------------------------------------------------
template <typename WT>
__global__ __launch_bounds__(256) void we_kernel(
    const float* __restrict__ efeat, const float* __restrict__ W,
    const float* __restrict__ b, WT* __restrict__ We, int E) {
  __shared__ float ef[32 * EF];
  const int t = threadIdx.x;
  const int e0 = blockIdx.x * 32;
  const int rem = E - e0;
  if (rem >= 32) {
    const float4* g4 = (const float4*)(efeat + (size_t)e0 * EF);
    float4* l4 = (float4*)ef;
    l4[t] = g4[t];
    l4[t + 256] = g4[t + 256];
  } else {
    for (int i = t; i < rem * EF; i += 256) ef[i] = efeat[(size_t)e0 * EF + i];
  }
  __syncthreads();
  const int cg = t & 63;   // 64 col-groups of 4 cols -> one wave covers 256 cols
  const int eg = t >> 6;   // 4 waves, 8 edges each
  const int c0 = blockIdx.y * 256 + cg * 4;
  const float4 bv = *(const float4*)(b + c0);
  float acc[8][4];
#pragma unroll
  for (int i = 0; i < 8; ++i) {
    acc[i][0] = bv.x; acc[i][1] = bv.y; acc[i][2] = bv.z; acc[i][3] = bv.w;
  }
#pragma unroll 8
  for (int k = 0; k < EF; ++k) {
    const float4 wv = *(const float4*)(W + (size_t)k * DD + c0);
#pragma unroll
    for (int i = 0; i < 8; ++i) {
      const float f = ef[(eg * 8 + i) * EF + k];  // wave-uniform -> LDS broadcast
      acc[i][0] += f * wv.x; acc[i][1] += f * wv.y;
      acc[i][2] += f * wv.z; acc[i][3] += f * wv.w;
    }
  }
#pragma unroll
  for (int i = 0; i < 8; ++i) {
    const int e = e0 + eg * 8 + i;
    if (e < E) {
      if constexpr (sizeof(WT) == 4) {
        // W_e is 3.2x L3 and re-read 3x sequentially: stream it (nt), one
        // vectorized global_store_dwordx4.
        floatx4 v = {acc[i][0], acc[i][1], acc[i][2], acc[i][3]};
        __builtin_nontemporal_store(
            v, (floatx4*)((float*)We + (size_t)e * DD + c0));
      } else {
        __hip_bfloat16* p = (__hip_bfloat16*)We + (size_t)e * DD + c0;
        p[0] = __float2bfloat16(acc[i][0]); p[1] = __float2bfloat16(acc[i][1]);
        p[2] = __float2bfloat16(acc[i][2]); p[3] = __float2bfloat16(acc[i][3]);
      }
    }
  }
}

// ---------------------------------------------------------------------------
// msg[e,o] = sum_d h[src[e],d] * We[e, d*32+o]; atomic scatter into a[dst[e]]
// 32 lanes per edge, 8 edges per 256-thread block. We is streamed sequentially
// (each k-iteration reads one 128B contiguous line per edge -> fully coalesced).
// ---------------------------------------------------------------------------
template <typename WT>
__global__ __launch_bounds__(256) void msg_kernel(
    const float* __restrict__ h, const WT* __restrict__ We,
    const int* __restrict__ src, const int* __restrict__ dst,
    float* __restrict__ a, int E) {
  const int t = threadIdx.x;
  const int o = t & 31;
  const int e = blockIdx.x * 8 + (t >> 5);
  if (e >= E) return;
  const int s = src[e];
  const int dn = dst[e];
  const float hv = h[(size_t)s * D + o];
  const WT* wrow = We + (size_t)e * DD;
  float acc = 0.0f;
#pragma unroll
  for (int k = 0; k < D; ++k) {
    const float hk = __shfl(hv, k, 32);
    acc += hk * wload(wrow + k * D + o);
  }
  atomicAdd(a + (size_t)dn * D + o, acc);
}

// ---------------------------------------------------------------------------
// Fallback (tiny workspace): recompute W_e on the fly. Correctness path only.
// ---------------------------------------------------------------------------
__global__ __launch_bounds__(256) void msg_fused_kernel(
    const float* __restrict__ h, const float* __restrict__ efeat,
    const float* __restrict__ W, const float* __restrict__ b,
    const int* __restrict__ src, const int* __restrict__ dst,
    float* __restrict__ a, int E) {
  const int t = threadIdx.x;
  const int o = t & 31;
  const int e = blockIdx.x * 8 + (t >> 5);
  if (e >= E) return;
  const int s = src[e];
  const int dn = dst[e];
  const float hv = h[(size_t)s * D + o];
  const float ef0 = efeat[(size_t)e * EF + o];
  const float ef1 = efeat[(size_t)e * EF + 32 + o];
  float acc = 0.0f;
  for (int dd = 0; dd < D; ++dd) {
    float w = b[dd * D + o];
#pragma unroll 8
    for (int f = 0; f < 32; ++f) {
      w += __shfl(ef0, f, 32) * W[(size_t)f * DD + dd * D + o];
      w += __shfl(ef1, f, 32) * W[(size_t)(f + 32) * DD + dd * D + o];
    }
    acc += __shfl(hv, dd, 32) * w;
  }
  atomicAdd(a + (size_t)dn * D + o, acc);
}

// ---------------------------------------------------------------------------
// GRUCell: 32 lanes per node, 8 nodes per block. W matrices staged transposed
// in LDS ([k][row] so lanes o=0..31 read consecutive addresses, conflict-free).
// ---------------------------------------------------------------------------
__global__ __launch_bounds__(256) void gru_kernel(
    const float* __restrict__ a, const float* __restrict__ h,
    const float* __restrict__ W_ih, const float* __restrict__ b_ih,
    const float* __restrict__ W_hh, const float* __restrict__ b_hh,
    float* __restrict__ out, int Nn) {
  __shared__ float wi[D * 96];
  __shared__ float wh[D * 96];
  const int t = threadIdx.x;
  for (int i = t; i < 96 * D; i += 256) {
    const int row = i >> 5, k = i & 31;
    wi[k * 96 + row] = W_ih[i];
    wh[k * 96 + row] = W_hh[i];
  }
  __syncthreads();
  const int o = t & 31;
  const int n = blockIdx.x * 8 + (t >> 5);
  if (n >= Nn) return;
  const float x = a[(size_t)n * D + o];
  const float hv = h[(size_t)n * D + o];
  float air = 0.f, aiz = 0.f, ain = 0.f, ahr = 0.f, ahz = 0.f, ahn = 0.f;
#pragma unroll
  for (int k = 0; k < D; ++k) {
    const float xk = __shfl(x, k, 32);
    const float hk = __shfl(hv, k, 32);
    const float* wik = wi + k * 96;
    const float* whk = wh + k * 96;
    air += wik[o] * xk;      ahr += whk[o] * hk;
    aiz += wik[32 + o] * xk; ahz += whk[32 + o] * hk;
    ain += wik[64 + o] * xk; ahn += whk[64 + o] * hk;
  }
  const float r = sigmoidf_(air + b_ih[o] + ahr + b_hh[o]);
  const float z = sigmoidf_(aiz + b_ih[32 + o] + ahz + b_hh[32 + o]);
  const float nn = tanhf(ain + b_ih[64 + o] + r * (ahn + b_hh[64 + o]));
  out[(size_t)n * D + o] = (1.0f - z) * nn + z * hv;
}

// ---------------------------------------------------------------------------
extern "C" void kernel_launch(void* const* d_in, const int* in_sizes, int n_in,
                              void* d_out, int out_size, void* d_ws, size_t ws_size,
                              hipStream_t stream) {
  const float* feat   = (const float*)d_in[0];
  const float* efeat  = (const float*)d_in[1];
  const float* W_edge = (const float*)d_in[2];
  const float* b_edge = (const float*)d_in[3];
  const float* W_ih   = (const float*)d_in[4];
  const float* b_ih   = (const float*)d_in[5];
  const float* W_hh   = (const float*)d_in[6];
  const float* b_hh   = (const float*)d_in[7];
  const int*   src    = (const int*)d_in[8];
  const int*   dst    = (const int*)d_in[9];
  float* out = (float*)d_out;
  const int Nn = in_sizes[0] / D;
  const int Ee = in_sizes[8];

  char* ws = (char*)d_ws;
  float* a    = (float*)ws;
  float* hbuf = (float*)(ws + (size_t)Nn * D * sizeof(float));
  char*  wep  = ws + 2 * (size_t)Nn * D * sizeof(float);
  const size_t base      = 2 * (size_t)Nn * D * sizeof(float);
  const size_t need_f32  = base + (size_t)Ee * DD * sizeof(float);
  const size_t need_bf16 = base + (size_t)Ee * DD * sizeof(__hip_bfloat16);
  // mode depends only on ws_size -> identical work every call (capture-safe)
  const int mode = (ws_size >= need_f32) ? 0 : (ws_size >= need_bf16 ? 1 : 2);

  const dim3 blk(256);
  if (mode == 0)
    we_kernel<float><<<dim3((Ee + 31) / 32, 4), blk, 0, stream>>>(
        efeat, W_edge, b_edge, (float*)wep, Ee);
  else if (mode == 1)
    we_kernel<__hip_bfloat16><<<dim3((Ee + 31) / 32, 4), blk, 0, stream>>>(
        efeat, W_edge, b_edge, (__hip_bfloat16*)wep, Ee);

  for (int step = 0; step < NSTEPS; ++step) {
    const float* hin = (step == 0) ? feat : hbuf;
    float* hout = (step == NSTEPS - 1) ? out : hbuf;
    (void)hipMemsetAsync(a, 0, (size_t)Nn * D * sizeof(float), stream);
    if (mode == 0)
      msg_kernel<float><<<(Ee + 7) / 8, blk, 0, stream>>>(
          hin, (const float*)wep, src, dst, a, Ee);
    else if (mode == 1)
      msg_kernel<__hip_bfloat16><<<(Ee + 7) / 8, blk, 0, stream>>>(
          hin, (const __hip_bfloat16*)wep, src, dst, a, Ee);
    else
      msg_fused_kernel<<<(Ee + 7) / 8, blk, 0, stream>>>(
          hin, efeat, W_edge, b_edge, src, dst, a, Ee);
    gru_kernel<<<(Nn + 7) / 8, blk, 0, stream>>>(
        a, hin, W_ih, b_ih, W_hh, b_hh, hout, Nn);
  }
}

// Round 7
// 2244.513 us; speedup vs baseline: 3.1136x; 3.1136x over previous
//
#include <hip/hip_runtime.h>
#include <hip/hip_bf16.h>
#include <cstddef>

#define D 32
#define EF 64
#define NSTEPS 3

#define NSPLIT 4            // f-slices (grid.y)
#define FS (EF / NSPLIT)    // 16 f-values per slice
#define TE 4                // edges per wave
#define WAVES 8
#define BLK (WAVES * 64)    // 512 threads
#define EPB (WAVES * TE)    // 32 edges per block

__device__ __forceinline__ float sigmoidf_(float x) { return 1.0f / (1.0f + expf(-x)); }

// ---------------------------------------------------------------------------
// msg[e,o] = sum_{f,dd} ef[e,f] * h[src[e],dd] * W[f,dd*32+o]  (+ bias rows)
// scattered into a[dst[e],o] via atomics.
//
// B = W_edge viewed as (2048 x 32), contiguous as stored. Each block stages a
// 16-f slice (64 KB) in LDS, reused by 32 edges. Wave = 2 dd-halves x 32 o.
// Each lane keeps h_src for its dd-half of TE edges in registers (static
// indexing only), so the inner loop is 1 ds_read + TE FMA per (f,dd) pair.
// ---------------------------------------------------------------------------
__global__ __launch_bounds__(BLK) void msg_gemm_kernel(
    const float* __restrict__ h, const float* __restrict__ efeat,
    const float* __restrict__ W, const float* __restrict__ bvec,
    const int* __restrict__ src, const int* __restrict__ dst,
    float* __restrict__ a, int E) {
  __shared__ float Blds[FS * D * D];  // [ff][dd][o], 64 KB
  const int t = threadIdx.x;
  const int f0 = blockIdx.y * FS;
  {
    // slice is contiguous: W[f0*1024 .. (f0+16)*1024)
    const float4* g4 = (const float4*)(W + (size_t)f0 * (D * D));
    float4* l4 = (float4*)Blds;
#pragma unroll
    for (int i = 0; i < (FS * D * D / 4) / BLK; ++i)  // 8 iters
      l4[t + i * BLK] = g4[t + i * BLK];
  }
  __syncthreads();

  const int wv = t >> 6;
  const int lane = t & 63;
  const int o = lane & 31;
  const int half = lane >> 5;       // dd-half: [16*half, 16*half+16)
  const int dbase = half * 16;
  const int ebase = blockIdx.x * EPB + wv * TE;
  const int sh0 = f0 & 16;          // shfl base within the loaded ef 32-half

  float hreg[TE][16];
  float efv[TE];
  int dn[TE];
  bool ok[TE];
#pragma unroll
  for (int j = 0; j < TE; ++j) {
    const int e = ebase + j;
    ok[j] = (e < E);
    const int s = ok[j] ? src[e] : 0;
    dn[j] = ok[j] ? dst[e] : 0;
    const float hv = ok[j] ? h[(size_t)s * D + o] : 0.0f;
    efv[j] = ok[j] ? efeat[(size_t)e * EF + (f0 & 32) + o] : 0.0f;
#pragma unroll
    for (int q = 0; q < 16; ++q)
      hreg[j][q] = __shfl(hv, dbase + q, 32);  // h[s][dbase+q], static reg idx
  }

  float acc[TE] = {0.f, 0.f, 0.f, 0.f};
  for (int ff = 0; ff < FS; ++ff) {
    float ef_f[TE];
#pragma unroll
    for (int j = 0; j < TE; ++j) ef_f[j] = __shfl(efv[j], sh0 + ff, 32);
    const float* Brow = Blds + ((size_t)(ff * D + dbase)) * D + o;
    float S[TE] = {0.f, 0.f, 0.f, 0.f};
#pragma unroll
    for (int q = 0; q < 16; ++q) {
      const float bv = Brow[q * D];  // bank = o, halves on distinct rows: 2-way (free)
#pragma unroll
      for (int j = 0; j < TE; ++j) S[j] += hreg[j][q] * bv;
    }
#pragma unroll
    for (int j = 0; j < TE; ++j) acc[j] += ef_f[j] * S[j];
  }

  if (blockIdx.y == 0) {  // bias rows once: msg += sum_dd h_dd * b[dd*32+o]
#pragma unroll
    for (int q = 0; q < 16; ++q) {
      const float bb = bvec[(dbase + q) * D + o];
#pragma unroll
      for (int j = 0; j < TE; ++j) acc[j] += hreg[j][q] * bb;
    }
  }

#pragma unroll
  for (int j = 0; j < TE; ++j) {
    const float v = acc[j] + __shfl_xor(acc[j], 32);  // combine dd-halves
    if (half == 0 && ok[j]) atomicAdd(a + (size_t)dn[j] * D + o, v);
  }
}

// ---------------------------------------------------------------------------
// GRUCell: 32 lanes per node, 8 nodes per block. W matrices staged transposed
// in LDS ([k][row] so lanes o=0..31 read consecutive addresses, conflict-free).
// ---------------------------------------------------------------------------
__global__ __launch_bounds__(256) void gru_kernel(
    const float* __restrict__ a, const float* __restrict__ h,
    const float* __restrict__ W_ih, const float* __restrict__ b_ih,
    const float* __restrict__ W_hh, const float* __restrict__ b_hh,
    float* __restrict__ out, int Nn) {
  __shared__ float wi[D * 96];
  __shared__ float wh[D * 96];
  const int t = threadIdx.x;
  for (int i = t; i < 96 * D; i += 256) {
    const int row = i >> 5, k = i & 31;
    wi[k * 96 + row] = W_ih[i];
    wh[k * 96 + row] = W_hh[i];
  }
  __syncthreads();
  const int o = t & 31;
  const int n = blockIdx.x * 8 + (t >> 5);
  if (n >= Nn) return;
  const float x = a[(size_t)n * D + o];
  const float hv = h[(size_t)n * D + o];
  float air = 0.f, aiz = 0.f, ain = 0.f, ahr = 0.f, ahz = 0.f, ahn = 0.f;
#pragma unroll
  for (int k = 0; k < D; ++k) {
    const float xk = __shfl(x, k, 32);
    const float hk = __shfl(hv, k, 32);
    const float* wik = wi + k * 96;
    const float* whk = wh + k * 96;
    air += wik[o] * xk;      ahr += whk[o] * hk;
    aiz += wik[32 + o] * xk; ahz += whk[32 + o] * hk;
    ain += wik[64 + o] * xk; ahn += whk[64 + o] * hk;
  }
  const float r = sigmoidf_(air + b_ih[o] + ahr + b_hh[o]);
  const float z = sigmoidf_(aiz + b_ih[32 + o] + ahz + b_hh[32 + o]);
  const float nn = tanhf(ain + b_ih[64 + o] + r * (ahn + b_hh[64 + o]));
  out[(size_t)n * D + o] = (1.0f - z) * nn + z * hv;
}

// ---------------------------------------------------------------------------
extern "C" void kernel_launch(void* const* d_in, const int* in_sizes, int n_in,
                              void* d_out, int out_size, void* d_ws, size_t ws_size,
                              hipStream_t stream) {
  const float* feat   = (const float*)d_in[0];
  const float* efeat  = (const float*)d_in[1];
  const float* W_edge = (const float*)d_in[2];
  const float* b_edge = (const float*)d_in[3];
  const float* W_ih   = (const float*)d_in[4];
  const float* b_ih   = (const float*)d_in[5];
  const float* W_hh   = (const float*)d_in[6];
  const float* b_hh   = (const float*)d_in[7];
  const int*   src    = (const int*)d_in[8];
  const int*   dst    = (const int*)d_in[9];
  float* out = (float*)d_out;
  const int Nn = in_sizes[0] / D;
  const int Ee = in_sizes[8];

  char* ws = (char*)d_ws;
  float* a    = (float*)ws;                                    // N*D f32
  float* hbuf = (float*)(ws + (size_t)Nn * D * sizeof(float)); // N*D f32

  const dim3 blk(BLK);
  const dim3 grid((Ee + EPB - 1) / EPB, NSPLIT);

  for (int step = 0; step < NSTEPS; ++step) {
    const float* hin = (step == 0) ? feat : hbuf;
    float* hout = (step == NSTEPS - 1) ? out : hbuf;
    (void)hipMemsetAsync(a, 0, (size_t)Nn * D * sizeof(float), stream);
    msg_gemm_kernel<<<grid, blk, 0, stream>>>(
        hin, efeat, W_edge, b_edge, src, dst, a, Ee);
    gru_kernel<<<(Nn + 7) / 8, 256, 0, stream>>>(
        a, hin, W_ih, b_ih, W_hh, b_hh, hout, Nn);
  }
}